// Round 2
// 335.778 us; speedup vs baseline: 1.0212x; 1.0212x over previous
//
#include <hip/hip_runtime.h>
#include <hip/hip_bf16.h>
#include <stdint.h>

typedef unsigned short u16;
typedef short bf16x8 __attribute__((ext_vector_type(8)));
typedef float f32x4 __attribute__((ext_vector_type(4)));

#define D_MODEL 1024
#define NHEAD 16
#define DK 64
#define SEQ 2048
#define NB 4
#define MTOT (NB * SEQ) /* 8192 */

__device__ __forceinline__ u16 f2bf(float f) {
  union { float f; unsigned u; } x; x.f = f;
  unsigned r = x.u + 0x7FFFu + ((x.u >> 16) & 1u);
  return (u16)(r >> 16);
}
#if __has_builtin(__builtin_amdgcn_cvt_pk_bf16_f32)
__device__ __forceinline__ unsigned pkbf(float a, float b) {
  auto r = __builtin_amdgcn_cvt_pk_bf16_f32(a, b);
  union { decltype(r) v; unsigned u; } c; c.v = r; return c.u;
}
#else
__device__ __forceinline__ unsigned pkbf(float a, float b) {
  return (unsigned)f2bf(a) | ((unsigned)f2bf(b) << 16);
}
#endif
#if __has_builtin(__builtin_amdgcn_exp2f)
__device__ __forceinline__ float exp2r(float x) { return __builtin_amdgcn_exp2f(x); }
#else
__device__ __forceinline__ float exp2r(float x) { return exp2f(x); }
#endif
__device__ __forceinline__ void gl_lds16(const u16* g, u16* s) {
  __builtin_amdgcn_global_load_lds(
      (const __attribute__((address_space(1))) void*)g,
      (__attribute__((address_space(3))) void*)s, 16, 0, 0);
}

// ---------- converters ----------
struct CvtArgs {
  const float4* s[7];
  uint2* d[7];
  int n4[7];
};
__global__ __launch_bounds__(256) void cvt_all(CvtArgs a) {
  const int y = blockIdx.y;
  const float4* s = a.s[y];
  uint2* d = a.d[y];
  const int n4 = a.n4[y];
  for (int i = blockIdx.x * 256 + threadIdx.x; i < n4; i += gridDim.x * 256) {
    float4 x = s[i];
    uint2 o;
    o.x = pkbf(x.x, x.y);
    o.y = pkbf(x.z, x.w);
    d[i] = o;
  }
}

// ---------- GEMM core: m97-style 128x128 tile, BK=64 ----------
// C = (A(8192x1024) @ W(1024x1024)^T + bias) * scale
// MODE 0: out (B,H,S,DK) bf16 scatter; MODE 1: out (B,H,DK,S) bf16 transpose;
// MODE 2: out (M,N) fp32.
template <int MODE>
__device__ __forceinline__ void gemm_body(
    const u16* __restrict__ A, const u16* __restrict__ W,
    const float* __restrict__ bias, void* __restrict__ out, float scale,
    int m0, int n0, u16* smem)
{
  u16* As = smem;
  u16* Bs = smem + 8192;

  const int tid = threadIdx.x;
  const int l = tid & 63, w = tid >> 6;
  const int wm = (w >> 1) << 6, wn = (w & 1) << 6;

  int srow[4], sk8[4], sdst[4];
#pragma unroll
  for (int r = 0; r < 4; ++r) {
    int c = r * 256 + tid;
    srow[r] = c >> 3;
    sk8[r] = (c & 7) ^ (srow[r] & 7);
    sdst[r] = c << 3;
  }
  int aoff[4][2], boff[4][2];
#pragma unroll
  for (int i = 0; i < 4; ++i) {
    int mr = wm + (i << 4) + (l & 15);
    int nr = wn + (i << 4) + (l & 15);
#pragma unroll
    for (int s = 0; s < 2; ++s) {
      int kc = (s << 2) + (l >> 4);
      aoff[i][s] = (mr << 6) + ((kc ^ (mr & 7)) << 3);
      boff[i][s] = (nr << 6) + ((kc ^ (nr & 7)) << 3);
    }
  }

  const u16* Ab = A + (size_t)m0 * D_MODEL;
  const u16* Bb = W + (size_t)n0 * D_MODEL;

  f32x4 acc[4][4] = {};

  for (int kt = 0; kt < 16; ++kt) {
    const int kbase = kt << 6;
#pragma unroll
    for (int r = 0; r < 4; ++r)
      gl_lds16(Ab + (size_t)srow[r] * D_MODEL + kbase + (sk8[r] << 3), As + sdst[r]);
#pragma unroll
    for (int r = 0; r < 4; ++r)
      gl_lds16(Bb + (size_t)srow[r] * D_MODEL + kbase + (sk8[r] << 3), Bs + sdst[r]);
    __syncthreads();
#pragma unroll
    for (int s = 0; s < 2; ++s) {
      bf16x8 af[4], bfv[4];
#pragma unroll
      for (int i = 0; i < 4; ++i) af[i] = *(const bf16x8*)(As + aoff[i][s]);
#pragma unroll
      for (int j = 0; j < 4; ++j) bfv[j] = *(const bf16x8*)(Bs + boff[j][s]);
#pragma unroll
      for (int i = 0; i < 4; ++i)
#pragma unroll
        for (int j = 0; j < 4; ++j)
          acc[i][j] = __builtin_amdgcn_mfma_f32_16x16x32_bf16(af[i], bfv[j], acc[i][j], 0, 0, 0);
    }
    __syncthreads();
  }

  if (MODE == 1) {
    u16* Cs = smem;  // [n=128][s=128] stride 136
    u16* outb = (u16*)out;
#pragma unroll
    for (int i = 0; i < 4; ++i)
#pragma unroll
      for (int j = 0; j < 4; ++j) {
        int sl = wm + (i << 4) + ((l >> 4) << 2);
        int nl = wn + (j << 4) + (l & 15);
        float bj = bias[n0 + nl];
        uint2 pk;
        pk.x = pkbf(acc[i][j][0] + bj, acc[i][j][1] + bj);
        pk.y = pkbf(acc[i][j][2] + bj, acc[i][j][3] + bj);
        *(uint2*)(Cs + nl * 136 + sl) = pk;
      }
    __syncthreads();
    int nl = tid >> 1, sh = (tid & 1) << 6;
    int n = n0 + nl;
    int b_ = m0 >> 11;
    const uint4* src = (const uint4*)(Cs + nl * 136 + sh);
    uint4* dst = (uint4*)(outb +
        (((size_t)b_ * NHEAD + (n >> 6)) * DK + (n & 63)) * SEQ + (m0 & 2047) + sh);
#pragma unroll
    for (int e = 0; e < 8; ++e) dst[e] = src[e];
  } else {
    u16* outb = (u16*)out;
    float* outf = (float*)out;
#pragma unroll
    for (int i = 0; i < 4; ++i)
#pragma unroll
      for (int j = 0; j < 4; ++j) {
        int ml = m0 + wm + (i << 4) + ((l >> 4) << 2);
        int n = n0 + wn + (j << 4) + (l & 15);
        float bj = bias[n];
#pragma unroll
        for (int r = 0; r < 4; ++r) {
          int m = ml + r;
          float v = (acc[i][j][r] + bj) * scale;
          if (MODE == 0)
            outb[(((size_t)(m >> 11) * NHEAD + (n >> 6)) * SEQ + (m & 2047)) * DK + (n & 63)] = f2bf(v);
          else
            outf[(size_t)m * D_MODEL + n] = v;
        }
      }
  }
}

// XCD-locality grids: grid (m=64, n=8[, z]); linear id % 8 == m-block % 8, so
// each XCD keeps its 8 A row-blocks (2 MB) + current W slice (256 KB) in its
// private 4 MB L2 across the n sweep.
template <int MODE>
__global__ __launch_bounds__(256) void gemm128(
    const u16* __restrict__ A, const u16* __restrict__ W,
    const float* __restrict__ bias, void* __restrict__ out, float scale)
{
  __shared__ alignas(16) u16 smem[17408];
  gemm_body<MODE>(A, W, bias, out, scale,
                  blockIdx.x << 7, blockIdx.y << 7, smem);
}

__global__ __launch_bounds__(256) void proj_qkv(
    const u16* __restrict__ Cq, const u16* __restrict__ Ck, const u16* __restrict__ Cv,
    const u16* __restrict__ wq, const u16* __restrict__ wk, const u16* __restrict__ wv,
    const float* __restrict__ bq, const float* __restrict__ bk, const float* __restrict__ bv,
    u16* __restrict__ Qb, u16* __restrict__ Kb, u16* __restrict__ Vt, float scq)
{
  __shared__ alignas(16) u16 smem[17408];
  const int z = blockIdx.z;
  const int m0 = blockIdx.x << 7, n0 = blockIdx.y << 7;
  if (z == 0)
    gemm_body<0>(Cq, wq, bq, Qb, scq, m0, n0, smem);
  else if (z == 1)
    gemm_body<0>(Ck, wk, bk, Kb, 1.0f, m0, n0, smem);
  else
    gemm_body<1>(Cv, wv, bv, Vt, 1.0f, m0, n0, smem);
}

// ---------- transposed flash attention, double-buffered K/V (T3-min) ----------
// 512 threads (8 waves x 32 q-rows), QBLK=256. grid (bh=64, q=8): 512 blocks =
// exactly 2 blocks/CU (16 waves). id%8 == bh%8 -> each XCD owns 8 heads' K/V in L2.
// Per tile t: issue stage(t+1) into alt buffer FIRST, then QK/softmax/PV on cur,
// then one __syncthreads() (vmcnt(0)+barrier) - stage latency hides under compute.
__global__ __launch_bounds__(512, 4) void attn_fused(
    const u16* __restrict__ Q,   // (B,H,S,DK), pre-scaled by log2e/8
    const u16* __restrict__ K,   // (B,H,S,DK)
    const u16* __restrict__ Vt,  // (B,H,DK,S)
    const int* __restrict__ mask,
    u16* __restrict__ X)         // (B,S,D_MODEL) bf16
{
  __shared__ alignas(16) u16 PQ[16384];     // 256x64: Q stage, then P tiles
  __shared__ alignas(16) u16 Ks[2][4096];   // 64x64 double-buffered
  __shared__ alignas(16) u16 Vs[2][4096];   // 64x64 double-buffered
  __shared__ alignas(16) u16 On[1024];      // 16x64 ones tile (row 0 = 1.0)
  __shared__ alignas(16) float mbf[2][64];

  const int tid = threadIdx.x;
  const int l = tid & 63, w = tid >> 6;
  const int lq = l & 15, qd = l >> 4;
  const int bh = blockIdx.x;
  const int q0 = blockIdx.y << 8;
  const int b_ = bh >> 4, h = bh & 15;
  const size_t base = (size_t)bh * SEQ * DK;
  const int wq0 = w << 5;

  // Q stage: 256 rows x 64 cols, swizzled
#pragma unroll
  for (int r = 0; r < 4; ++r) {
    int c = r * 512 + tid;
    int row = c >> 3, k8 = (c & 7) ^ (row & 7);
    gl_lds16(Q + base + (size_t)(q0 + row) * DK + (k8 << 3), PQ + (c << 3));
  }
  // ones tile: row 0 = 1.0, rows 1..15 = 0 (denominator trick, init once)
  if (tid < 256) {
    unsigned v = (tid < 16) ? 0x3F803F80u : 0u;
    uint2 pk; pk.x = v; pk.y = v;
    *(uint2*)(On + tid * 4) = pk;
  }
  // prologue: stage K/V tile 0 into buffer 0
  {
    int row = tid >> 3, k8 = (tid & 7) ^ (row & 7);
    gl_lds16(K + base + (size_t)row * DK + (k8 << 3), Ks[0] + (tid << 3));
    gl_lds16(Vt + base + (size_t)row * SEQ + (k8 << 3), Vs[0] + (tid << 3));
  }
  if (tid < 64) mbf[0][tid] = mask[b_ * SEQ + tid] ? 0.0f : -1.44269504e9f;
  __syncthreads();

  bf16x8 qf[2][2];
#pragma unroll
  for (int i = 0; i < 2; ++i)
#pragma unroll
    for (int s = 0; s < 2; ++s) {
      int row = wq0 + (i << 4) + lq;
      qf[i][s] = *(const bf16x8*)(PQ + (row << 6) + ((((s << 2) + qd) ^ (row & 7)) << 3));
    }

  f32x4 Ov[2][4] = {};
  f32x4 Ovl[2] = {};

  for (int t = 0; t < 32; ++t) {
    const int cur = t & 1;
    // ---- issue next tile's stage first: hides under this tile's compute ----
    if (t + 1 < 32) {
      const int kv1 = (t + 1) << 6;
      int row = tid >> 3, k8 = (tid & 7) ^ (row & 7);
      gl_lds16(K + base + (size_t)(kv1 + row) * DK + (k8 << 3), Ks[cur ^ 1] + (tid << 3));
      gl_lds16(Vt + base + (size_t)row * SEQ + kv1 + (k8 << 3), Vs[cur ^ 1] + (tid << 3));
      if (tid < 64) mbf[cur ^ 1][tid] = mask[b_ * SEQ + kv1 + tid] ? 0.0f : -1.44269504e9f;
    }

    float4 m4[4];
#pragma unroll
    for (int jb = 0; jb < 4; ++jb) m4[jb] = *(const float4*)(mbf[cur] + (jb << 4) + (qd << 2));

    f32x4 Sc[4][2];
#pragma unroll
    for (int jb = 0; jb < 4; ++jb)
#pragma unroll
      for (int i = 0; i < 2; ++i) {
        Sc[jb][i][0] = m4[jb].x; Sc[jb][i][1] = m4[jb].y;
        Sc[jb][i][2] = m4[jb].z; Sc[jb][i][3] = m4[jb].w;
      }
    const u16* Kc = Ks[cur];
    const u16* Vc = Vs[cur];
#pragma unroll
    for (int s = 0; s < 2; ++s) {
      bf16x8 kf[4];
#pragma unroll
      for (int jb = 0; jb < 4; ++jb) {
        int row = (jb << 4) + lq;
        kf[jb] = *(const bf16x8*)(Kc + (row << 6) + ((((s << 2) + qd) ^ (row & 7)) << 3));
      }
#pragma unroll
      for (int jb = 0; jb < 4; ++jb)
#pragma unroll
        for (int i = 0; i < 2; ++i)
          Sc[jb][i] = __builtin_amdgcn_mfma_f32_16x16x32_bf16(kf[jb], qf[i][s], Sc[jb][i], 0, 0, 0);
    }

#pragma unroll
    for (int i = 0; i < 2; ++i) {
      const int prow = wq0 + (i << 4) + lq;
      const int rbase = prow << 6;
      const int rsw = prow & 7;
#pragma unroll
      for (int jb = 0; jb < 4; ++jb) {
        float p0 = exp2r(Sc[jb][i][0]);
        float p1 = exp2r(Sc[jb][i][1]);
        float p2 = exp2r(Sc[jb][i][2]);
        float p3 = exp2r(Sc[jb][i][3]);
        uint2 pk;
        pk.x = pkbf(p0, p1);
        pk.y = pkbf(p2, p3);
        int c = (jb << 1) + (qd >> 1);
        *(uint2*)(PQ + rbase + ((c ^ rsw) << 3) + ((qd & 1) << 2)) = pk;
      }
    }

#pragma unroll
    for (int s = 0; s < 2; ++s) {
      bf16x8 pf[2], vf[4], vf1;
#pragma unroll
      for (int i = 0; i < 2; ++i) {
        int prow = wq0 + (i << 4) + lq;
        pf[i] = *(const bf16x8*)(PQ + (prow << 6) + ((((s << 2) + qd) ^ (prow & 7)) << 3));
      }
#pragma unroll
      for (int j = 0; j < 4; ++j) {
        int row = (j << 4) + lq;
        vf[j] = *(const bf16x8*)(Vc + (row << 6) + ((((s << 2) + qd) ^ (row & 7)) << 3));
      }
      vf1 = *(const bf16x8*)(On + (lq << 6) + ((((s << 2) + qd) ^ (lq & 7)) << 3));
#pragma unroll
      for (int i = 0; i < 2; ++i) {
#pragma unroll
        for (int j = 0; j < 4; ++j)
          Ov[i][j] = __builtin_amdgcn_mfma_f32_16x16x32_bf16(pf[i], vf[j], Ov[i][j], 0, 0, 0);
        Ovl[i] = __builtin_amdgcn_mfma_f32_16x16x32_bf16(pf[i], vf1, Ovl[i], 0, 0, 0);
      }
    }
    __syncthreads();
  }

#pragma unroll
  for (int i = 0; i < 2; ++i) {
    float inv[4];
#pragma unroll
    for (int r = 0; r < 4; ++r) inv[r] = 1.0f / Ovl[i][r];
#pragma unroll
    for (int r = 0; r < 4; ++r) {
      float sc_ = __shfl(inv[r], l & 48);
      int qrow = q0 + wq0 + (i << 4) + (qd << 2) + r;
#pragma unroll
      for (int j = 0; j < 4; ++j)
        X[((size_t)b_ * SEQ + qrow) * D_MODEL + (h << 6) + (j << 4) + lq] =
            f2bf(Ov[i][j][r] * sc_);
    }
  }
}

extern "C" void kernel_launch(void* const* d_in, const int* in_sizes, int n_in,
                              void* d_out, int out_size, void* d_ws, size_t ws_size,
                              hipStream_t stream) {
  const float* query = (const float*)d_in[0];
  const float* key_  = (const float*)d_in[1];
  const float* value = (const float*)d_in[2];
  const int* mask    = (const int*)d_in[3];
  const float* Wq = (const float*)d_in[4];
  const float* bq = (const float*)d_in[5];
  const float* Wk = (const float*)d_in[6];
  const float* bk = (const float*)d_in[7];
  const float* Wv = (const float*)d_in[8];
  const float* bv = (const float*)d_in[9];
  const float* Wo = (const float*)d_in[10];
  const float* bo = (const float*)d_in[11];

  u16* ws16 = (u16*)d_ws;
  const size_t WSZ = (size_t)D_MODEL * D_MODEL;   // 1M elems
  const size_t ASZ = (size_t)MTOT * D_MODEL;      // 8M elems
  const float SCQ = 0.125f * 1.44269504088896f;   // 1/sqrt(dk) * log2(e)

  dim3 blk(256);
  dim3 gg(MTOT / 128, D_MODEL / 128);             // (64, 8): id%8 = m-block%8

  if (ws_size >= (size_t)(4 * WSZ + 4 * ASZ) * 2) {
    // ---- fast path: 4 launches; Cv & V^T live in d_out ----
    u16* wqc = ws16;
    u16* wkc = ws16 + WSZ;
    u16* wvc = ws16 + 2 * WSZ;
    u16* woc = ws16 + 3 * WSZ;
    u16* Cq  = ws16 + 4 * WSZ;
    u16* Ck  = ws16 + 4 * WSZ + ASZ;
    u16* Qb  = ws16 + 4 * WSZ + 2 * ASZ;
    u16* Kb  = ws16 + 4 * WSZ + 3 * ASZ;
    u16* Xb  = Cq;                       // reused after proj_qkv consumed Cq
    u16* Vtb = (u16*)d_out;              // bf16, first 16 MB of d_out
    u16* Cv  = (u16*)d_out + ASZ;        // bf16, second 16 MB of d_out

    CvtArgs ca;
    ca.s[0] = (const float4*)query; ca.d[0] = (uint2*)Cq;  ca.n4[0] = (int)(ASZ / 4);
    ca.s[1] = (const float4*)key_;  ca.d[1] = (uint2*)Ck;  ca.n4[1] = (int)(ASZ / 4);
    ca.s[2] = (const float4*)value; ca.d[2] = (uint2*)Cv;  ca.n4[2] = (int)(ASZ / 4);
    ca.s[3] = (const float4*)Wq;    ca.d[3] = (uint2*)wqc; ca.n4[3] = (int)(WSZ / 4);
    ca.s[4] = (const float4*)Wk;    ca.d[4] = (uint2*)wkc; ca.n4[4] = (int)(WSZ / 4);
    ca.s[5] = (const float4*)Wv;    ca.d[5] = (uint2*)wvc; ca.n4[5] = (int)(WSZ / 4);
    ca.s[6] = (const float4*)Wo;    ca.d[6] = (uint2*)woc; ca.n4[6] = (int)(WSZ / 4);

    cvt_all<<<dim3(512, 7), blk, 0, stream>>>(ca);
    proj_qkv<<<dim3(MTOT / 128, D_MODEL / 128, 3), blk, 0, stream>>>(
        Cq, Ck, Cv, wqc, wkc, wvc, bq, bk, bv, Qb, Kb, Vtb, SCQ);
    attn_fused<<<dim3(NB * NHEAD, SEQ / 256), dim3(512), 0, stream>>>(Qb, Kb, Vtb, mask, Xb);
    gemm128<2><<<gg, blk, 0, stream>>>(Xb, woc, bo, d_out, 1.0f);
  } else {
    // ---- fallback (56 MB ws): serialized, same kernels ----
    u16* wqc = ws16;
    u16* wkc = ws16 + WSZ;
    u16* wvc = ws16 + 2 * WSZ;
    u16* woc = ws16 + 3 * WSZ;
    u16* C1  = ws16 + 4 * WSZ;
    u16* Qb  = ws16 + 4 * WSZ + ASZ;
    u16* Kb  = ws16 + 4 * WSZ + 2 * ASZ;
    u16* Xb  = C1;
    u16* Vtb = (u16*)d_out;

    CvtArgs cw;
    for (int i = 0; i < 7; ++i) { cw.s[i] = (const float4*)Wq; cw.d[i] = (uint2*)wqc; cw.n4[i] = 0; }
    cw.s[0] = (const float4*)Wq; cw.d[0] = (uint2*)wqc; cw.n4[0] = (int)(WSZ / 4);
    cw.s[1] = (const float4*)Wk; cw.d[1] = (uint2*)wkc; cw.n4[1] = (int)(WSZ / 4);
    cw.s[2] = (const float4*)Wv; cw.d[2] = (uint2*)wvc; cw.n4[2] = (int)(WSZ / 4);
    cw.s[3] = (const float4*)Wo; cw.d[3] = (uint2*)woc; cw.n4[3] = (int)(WSZ / 4);

    cvt_all<<<dim3(512, 4), blk, 0, stream>>>(cw);
    CvtArgs c1;
    c1.s[0] = (const float4*)query; c1.d[0] = (uint2*)C1; c1.n4[0] = (int)(ASZ / 4);
    cvt_all<<<dim3(1024, 1), blk, 0, stream>>>(c1);
    gemm128<0><<<gg, blk, 0, stream>>>(C1, wqc, bq, Qb, SCQ);
    c1.s[0] = (const float4*)key_;
    cvt_all<<<dim3(1024, 1), blk, 0, stream>>>(c1);
    gemm128<0><<<gg, blk, 0, stream>>>(C1, wkc, bk, Kb, 1.0f);
    c1.s[0] = (const float4*)value;
    cvt_all<<<dim3(1024, 1), blk, 0, stream>>>(c1);
    gemm128<1><<<gg, blk, 0, stream>>>(C1, wvc, bv, Vtb, 1.0f);
    attn_fused<<<dim3(NB * NHEAD, SEQ / 256), dim3(512), 0, stream>>>(Qb, Kb, Vtb, mask, Xb);
    gemm128<2><<<gg, blk, 0, stream>>>(Xb, woc, bo, d_out, 1.0f);
  }
}